// Round 19
// baseline (44.332 us; speedup 1.0000x reference)
//
#include <hip/hip_runtime.h>
#include <math.h>

#define BB 4
#define CC 64
#define OO 64
#define HH 128
#define WW 128
#define HWsz (HH * WW)

typedef __attribute__((ext_vector_type(8))) _Float16 half8;
typedef __attribute__((ext_vector_type(4))) float floatx4;

// ---------------------------------------------------------------------------
// pre: (blocks 0..511)  x NCHW f32 -> xh merged NHWC f16 (px = 128B = 1 line)
//      (blocks 512..727) fragment-ordered f16 weight repack:
//  waf[((k*2+kh)*4+m)*512 + lane*8 + j], wcf[((k*2+kh)*2+m)*512 + lane*8 + j]
// ---------------------------------------------------------------------------
__global__ __launch_bounds__(256) void pre_kernel(
    const float* __restrict__ x, const float* __restrict__ wgt,
    const float* __restrict__ ow, const float* __restrict__ mw,
    _Float16* __restrict__ xh, _Float16* __restrict__ waf,
    _Float16* __restrict__ wcf)
{
    int bid = blockIdx.x;
    int tid = threadIdx.x;
    if (bid < 512) {
        int b = bid >> 7, y = bid & 127;
        int px = tid & 127;
        int ch = (tid >> 7) * 32;
        const float* xp = x + (size_t)(b * CC + ch) * HWsz + y * WW + px;
        _Float16 buf[32];
#pragma unroll
        for (int q = 0; q < 32; ++q)
            buf[q] = (_Float16)xp[(size_t)q * HWsz];
        _Float16* dst = xh + ((size_t)(b * HH + y) * WW + px) * 64 + ch;
#pragma unroll
        for (int q = 0; q < 4; ++q)
            *(half8*)&dst[q * 8] = *(const half8*)&buf[q * 8];
    } else {
        int i = (bid - 512) * 256 + tid;
        if (i < 36864) {
            int j = i & 7, lane = (i >> 3) & 63, rest = i >> 9;
            int m = rest & 3, kh = (rest >> 2) & 1, k = rest >> 3;
            int o = m * 16 + (lane & 15);
            int c = kh * 32 + ((lane >> 4) << 3) + j;
            waf[i] = (_Float16)wgt[o * 576 + c * 9 + k];
        } else if (i < 55296) {
            int t = i - 36864;
            int j = t & 7, lane = (t >> 3) & 63, rest = t >> 9;
            int m = rest & 1, kh = (rest >> 1) & 1, k = rest >> 2;
            int o = m * 16 + (lane & 15);
            int c = kh * 32 + ((lane >> 4) << 3) + j;
            float v = 0.f;
            if (o < 18) v = ow[o * 576 + c * 9 + k];
            else if (o < 27) v = mw[(o - 18) * 576 + c * 9 + k];
            wcf[t] = (_Float16)v;
        }
    }
}

// ---------------------------------------------------------------------------
// fused kernel (fp16, FULL-LINE gathers + CROSS-TAP-PIPELINED LDS bounce).
// 256 blocks x 1024 thr = 1 block/CU, 16 waves = 4 rows x 4 strips x 64-px
// column half. Phase 2 per iter: LDS-read tap k (written LAST iter -> no
// stall), issue tap k+1 full-line gathers, MFMA tap k, blend+write tap k+1.
// The produce chain (gather->blend->write) and consume chain (read->MFMA)
// overlap instead of serializing within one tap.
// ---------------------------------------------------------------------------
__global__ __launch_bounds__(1024, 1) void fused_kernel(
    const _Float16* __restrict__ xh, const _Float16* __restrict__ waf,
    const _Float16* __restrict__ wcf, const float* __restrict__ ob,
    const float* __restrict__ mb, float* __restrict__ out)
{
    __shared__ __align__(16) _Float16 lds_waf[36864];     // 73728 B
    __shared__ _Float16 omh[16 * 27 * 16];                // 13824 B
    __shared__ __align__(16) _Float16 blendb[16 * 2048];  // 65536 B

    int tid = threadIdx.x;
    int gid = blockIdx.x;
    // XCD swizzle: 256 blocks = 8 XCDs x 32 contiguous region-tiles
    int sid = (gid & 7) * 32 + (gid >> 3);
    int b = sid >> 6;
    int t = sid & 63;
    int rq = t >> 1;
    int q = t & 1;

    int wv = tid >> 6;         // 0..15
    int lane = tid & 63;
    int s = wv & 3;            // strip
    int h = rq * 4 + (wv >> 2);
    int p0 = q << 6;
    int g = lane >> 4;
    int pl = lane & 15;
    int goff = g * 8;
    int xw = p0 + s * 16 + pl;
    int oct = lane & 7;        // phase-2 gather: channel octet
    int pxg = lane >> 3;       // phase-2 gather: pixel within 8-px group

    const _Float16* xhb = xh + ((size_t)b << 20);
    _Float16* omw = &omh[wv * 27 * 16];
    _Float16* bbw = &blendb[wv * 2048];

    // ---- waves 0-7: issue weight staging loads (written to LDS later)
    half8 stg[9];
    if (wv < 8) {
#pragma unroll
        for (int i = 0; i < 9; ++i)
            stg[i] = *(const half8*)(waf + ((wv * 9 + i) << 9) + lane * 8);
    }

    // ---------------- phase 1: offset/mask conv (pipelined, f16) -----------
    floatx4 accC0 = {0.f, 0.f, 0.f, 0.f};
    floatx4 accC1 = {0.f, 0.f, 0.f, 0.f};

#define CADDR(K, P, V) do {                                                  \
    int ky = (K) / 3, kx = (K) - ky * 3;                                     \
    int yy = h + ky - 1, xx = xw + kx - 1;                                   \
    V = (yy >= 0) & (yy < HH) & (xx >= 0) & (xx < WW);                       \
    int yc = min(max(yy, 0), HH - 1), xc = min(max(xx, 0), WW - 1);          \
    P = ((yc * WW + xc) << 6) + goff;                                        \
} while (0)

#define CONVTAP(K, S0, S1, V) do {                                           \
    const _Float16* wp = wcf + ((K) << 11) + lane * 8;                       \
    half8 w00 = *(const half8*)(wp + (0 << 9));                              \
    half8 w01 = *(const half8*)(wp + (1 << 9));                              \
    half8 w10 = *(const half8*)(wp + (2 << 9));                              \
    half8 w11 = *(const half8*)(wp + (3 << 9));                              \
    half8 z = {0, 0, 0, 0, 0, 0, 0, 0};                                     \
    half8 a0 = (V) ? S0 : z;                                                 \
    half8 a1 = (V) ? S1 : z;                                                 \
    accC0 = __builtin_amdgcn_mfma_f32_16x16x32_f16(w00, a0, accC0, 0, 0, 0); \
    accC1 = __builtin_amdgcn_mfma_f32_16x16x32_f16(w01, a0, accC1, 0, 0, 0); \
    accC0 = __builtin_amdgcn_mfma_f32_16x16x32_f16(w10, a1, accC0, 0, 0, 0); \
    accC1 = __builtin_amdgcn_mfma_f32_16x16x32_f16(w11, a1, accC1, 0, 0, 0); \
} while (0)

    {
        bool vA, vB;
        int pa, pb;
        half8 A0, A1, B0, B1;
        CADDR(0, pa, vA);
        A0 = *(const half8*)(xhb + pa);
        A1 = *(const half8*)(xhb + pa + 32);
#pragma unroll 1
        for (int kp = 0; kp < 4; ++kp) {
            int k = kp * 2;
            CADDR(k + 1, pb, vB);
            B0 = *(const half8*)(xhb + pb);
            B1 = *(const half8*)(xhb + pb + 32);
            CONVTAP(k, A0, A1, vA);
            CADDR(k + 2, pa, vA);
            A0 = *(const half8*)(xhb + pa);
            A1 = *(const half8*)(xhb + pa + 32);
            CONVTAP(k + 1, B0, B1, vB);
        }
        CONVTAP(8, A0, A1, vA);
    }

    // om epilogue (wave-local, f16)
#pragma unroll
    for (int j = 0; j < 4; ++j) {
        int o = g * 4 + j;
        omw[o * 16 + pl] = (_Float16)(accC0[j] + ob[o]);
        int o2 = 16 + g * 4 + j;
        float v = accC1[j];
        if (o2 < 18) omw[o2 * 16 + pl] = (_Float16)(v + ob[o2]);
        else if (o2 < 27)
            omw[o2 * 16 + pl] =
                (_Float16)(1.0f / (1.0f + expf(-(v + mb[o2 - 18]))));
    }

    // ---- weights reg -> LDS (waves 0-7), single barrier
    if (wv < 8) {
#pragma unroll
        for (int i = 0; i < 9; ++i)
            *(half8*)&lds_waf[((wv * 9 + i) << 9) + lane * 8] = stg[i];
    }
    __syncthreads();

    // ---------------- phase 2: pipelined full-line gathers + GEMM ----------
    floatx4 acc0 = {0.f, 0.f, 0.f, 0.f}, acc1 = {0.f, 0.f, 0.f, 0.f};
    floatx4 acc2 = {0.f, 0.f, 0.f, 0.f}, acc3 = {0.f, 0.f, 0.f, 0.f};

// tap params for pixel P (0..15 in strip); this lane's channel octet `oct`
#define MKT(K, P, U00, U01, U10, U11, I00, I01, I10, I11) do {               \
    int ky = (K) / 3, kx = (K) - ky * 3;                                     \
    float oy = (float)omw[(2 * (K)) * 16 + (P)];                             \
    float ox = (float)omw[(2 * (K) + 1) * 16 + (P)];                         \
    float mk = (float)omw[(18 + (K)) * 16 + (P)];                            \
    float py = oy + (float)(h + ky - 1);                                     \
    float qx = ox + (float)(p0 + s * 16 + (P) + kx - 1);                     \
    float y0f = floorf(py), x0f = floorf(qx);                                \
    float dyy = py - y0f, dxx = qx - x0f;                                    \
    int y0 = (int)y0f, x0 = (int)x0f;                                        \
    int y1 = y0 + 1, x1 = x0 + 1;                                            \
    bool vy0 = (y0 >= 0) & (y0 < HH), vy1 = (y1 >= 0) & (y1 < HH);           \
    bool vx0 = (x0 >= 0) & (x0 < WW), vx1 = (x1 >= 0) & (x1 < WW);           \
    U00 = (vy0 & vx0) ? (1.f - dyy) * (1.f - dxx) * mk : 0.f;                \
    U01 = (vy0 & vx1) ? (1.f - dyy) * dxx * mk : 0.f;                        \
    U10 = (vy1 & vx0) ? dyy * (1.f - dxx) * mk : 0.f;                        \
    U11 = (vy1 & vx1) ? dyy * dxx * mk : 0.f;                                \
    int yc0 = min(max(y0, 0), HH - 1), yc1 = min(max(y1, 0), HH - 1);        \
    int xc0 = min(max(x0, 0), WW - 1), xc1 = min(max(x1, 0), WW - 1);        \
    I00 = ((yc0 * WW + xc0) << 6) + oct * 8;                                 \
    I01 = ((yc0 * WW + xc1) << 6) + oct * 8;                                 \
    I10 = ((yc1 * WW + xc0) << 6) + oct * 8;                                 \
    I11 = ((yc1 * WW + xc1) << 6) + oct * 8;                                 \
} while (0)

#define SPLAT8(H) ((half8){(H), (H), (H), (H), (H), (H), (H), (H)})
#define MF(Q, B, A) A = __builtin_amdgcn_mfma_f32_16x16x32_f16(Q, B, A, 0, 0, 0)

#define DECLG(S)                                                             \
    float u0##S, u1##S, u2##S, u3##S, u4##S, u5##S, u6##S, u7##S;            \
    half8 r0##S, r1##S, r2##S, r3##S, r4##S, r5##S, r6##S, r7##S;

// issue tap K's 8 full-line gathers into register set S
#define GLOAD(K, S) do {                                                     \
    int i0, i1, i2, i3, i4, i5, i6, i7;                                      \
    MKT(K, pxg, u0##S, u1##S, u2##S, u3##S, i0, i1, i2, i3);                 \
    MKT(K, 8 + pxg, u4##S, u5##S, u6##S, u7##S, i4, i5, i6, i7);             \
    r0##S = *(const half8*)(xhb + i0);                                       \
    r1##S = *(const half8*)(xhb + i1);                                       \
    r2##S = *(const half8*)(xhb + i2);                                       \
    r3##S = *(const half8*)(xhb + i3);                                       \
    r4##S = *(const half8*)(xhb + i4);                                       \
    r5##S = *(const half8*)(xhb + i5);                                       \
    r6##S = *(const half8*)(xhb + i6);                                       \
    r7##S = *(const half8*)(xhb + i7);                                       \
} while (0)

// blend set S and write to tap K's bounce buffer (buf K&1)
#define BW(K, S) do {                                                        \
    half8 bfA = r0##S * SPLAT8((_Float16)u0##S);                             \
    bfA = bfA + r1##S * SPLAT8((_Float16)u1##S);                             \
    bfA = bfA + r2##S * SPLAT8((_Float16)u2##S);                             \
    bfA = bfA + r3##S * SPLAT8((_Float16)u3##S);                             \
    half8 bfB = r4##S * SPLAT8((_Float16)u4##S);                             \
    bfB = bfB + r5##S * SPLAT8((_Float16)u5##S);                             \
    bfB = bfB + r6##S * SPLAT8((_Float16)u6##S);                             \
    bfB = bfB + r7##S * SPLAT8((_Float16)u7##S);                             \
    _Float16* bb = bbw + (((K) & 1) << 10);                                  \
    *(half8*)&bb[(pxg << 6) + ((oct ^ pxg) << 3)] = bfA;                     \
    *(half8*)&bb[((8 + pxg) << 6) + ((oct ^ pxg) << 3)] = bfB;               \
} while (0)

// consume tap K: read its bounce buffer (written last iter) + 8 MFMA
#define CONS(K) do {                                                         \
    const _Float16* bbr = bbw + (((K) & 1) << 10);                           \
    half8 bf = *(const half8*)&bbr[(pl << 6) + ((g ^ (pl & 7)) << 3)];       \
    half8 bd = *(const half8*)&bbr[(pl << 6) + (((g + 4) ^ (pl & 7)) << 3)]; \
    const _Float16* wk = &lds_waf[((K) << 12) + lane * 8];                   \
    half8 q0 = *(const half8*)(wk + (0 << 9));                               \
    half8 q1 = *(const half8*)(wk + (1 << 9));                               \
    half8 q2 = *(const half8*)(wk + (2 << 9));                               \
    half8 q3 = *(const half8*)(wk + (3 << 9));                               \
    half8 q4 = *(const half8*)(wk + (4 << 9));                               \
    half8 q5 = *(const half8*)(wk + (5 << 9));                               \
    half8 q6 = *(const half8*)(wk + (6 << 9));                               \
    half8 q7 = *(const half8*)(wk + (7 << 9));                               \
    MF(q0, bf, acc0); MF(q1, bf, acc1); MF(q2, bf, acc2); MF(q3, bf, acc3);  \
    MF(q4, bd, acc0); MF(q5, bd, acc1); MF(q6, bd, acc2); MF(q7, bd, acc3);  \
} while (0)

// iteration: read+MFMA tap K while producing tap K+1
#define ITER(K, S) do {                                                      \
    const _Float16* bbr = bbw + (((K) & 1) << 10);                           \
    half8 bf = *(const half8*)&bbr[(pl << 6) + ((g ^ (pl & 7)) << 3)];       \
    half8 bd = *(const half8*)&bbr[(pl << 6) + (((g + 4) ^ (pl & 7)) << 3)]; \
    GLOAD((K) + 1, S);                                                       \
    const _Float16* wk = &lds_waf[((K) << 12) + lane * 8];                   \
    half8 q0 = *(const half8*)(wk + (0 << 9));                               \
    half8 q1 = *(const half8*)(wk + (1 << 9));                               \
    half8 q2 = *(const half8*)(wk + (2 << 9));                               \
    half8 q3 = *(const half8*)(wk + (3 << 9));                               \
    half8 q4 = *(const half8*)(wk + (4 << 9));                               \
    half8 q5 = *(const half8*)(wk + (5 << 9));                               \
    half8 q6 = *(const half8*)(wk + (6 << 9));                               \
    half8 q7 = *(const half8*)(wk + (7 << 9));                               \
    MF(q0, bf, acc0); MF(q1, bf, acc1); MF(q2, bf, acc2); MF(q3, bf, acc3);  \
    MF(q4, bd, acc0); MF(q5, bd, acc1); MF(q6, bd, acc2); MF(q7, bd, acc3);  \
    BW((K) + 1, S);                                                          \
} while (0)

    {
        DECLG(A)
        DECLG(B)
        // prologue: produce tap 0
        GLOAD(0, A);
        BW(0, A);
        ITER(0, B);   // consume 0, produce 1
        ITER(1, A);   // consume 1, produce 2
        ITER(2, B);
        ITER(3, A);
        ITER(4, B);
        ITER(5, A);
        ITER(6, B);
        ITER(7, A);   // consume 7, produce 8
        CONS(8);      // consume 8
    }

    // epilogue: D col = pl, row o = m*16 + g*4 + j
    float* outp = out + (size_t)b * OO * HWsz + h * WW + p0 + s * 16 + pl;
#pragma unroll
    for (int j = 0; j < 4; ++j) outp[(size_t)(g * 4 + j) * HWsz] = acc0[j];
#pragma unroll
    for (int j = 0; j < 4; ++j) outp[(size_t)(16 + g * 4 + j) * HWsz] = acc1[j];
#pragma unroll
    for (int j = 0; j < 4; ++j) outp[(size_t)(32 + g * 4 + j) * HWsz] = acc2[j];
#pragma unroll
    for (int j = 0; j < 4; ++j) outp[(size_t)(48 + g * 4 + j) * HWsz] = acc3[j];
}

extern "C" void kernel_launch(void* const* d_in, const int* in_sizes, int n_in,
                              void* d_out, int out_size, void* d_ws, size_t ws_size,
                              hipStream_t stream)
{
    const float* x   = (const float*)d_in[0];
    const float* ow  = (const float*)d_in[1];
    const float* ob  = (const float*)d_in[2];
    const float* mw  = (const float*)d_in[3];
    const float* mb  = (const float*)d_in[4];
    const float* wgt = (const float*)d_in[5];
    float* out = (float*)d_out;

    // ws: xh (4*16384*64 f16 = 8.39MB) | waf (36864 f16) | wcf (18432 f16)
    _Float16* xh  = (_Float16*)d_ws;
    _Float16* waf = xh + (size_t)BB * HWsz * 64;
    _Float16* wcf = waf + 36864;

    pre_kernel<<<dim3(512 + 216), dim3(256), 0, stream>>>(
        x, wgt, ow, mw, xh, waf, wcf);
    fused_kernel<<<dim3(256), dim3(1024), 0, stream>>>(
        xh, waf, wcf, ob, mb, out);
}